// Round 15
// baseline (103.382 us; speedup 1.0000x reference)
//
#include <hip/hip_runtime.h>
#include <math.h>
#include <stdint.h>

#define KCODES 512
#define DIM 64
#define NROWS (64 * 4096)     // B*S = 262144
#define BLOCK 256             // 4 waves, persistent
#define NBLK 512              // 2048 waves x 128 rows/wave = NROWS
#define ROWS_PER_WAVE 128

typedef float f32x4 __attribute__((ext_vector_type(4)));
typedef long long i64t;

// ---------------------------------------------------------------------------
// Kernel A (prep, runs once): per code k
//   en512[k] = 512 * (1 + ||e_k||^2)   (exact fp32)
//   ebf8[k*64 + j*8 ..] = fp8_e4m3(-1024 * e_k[j*8..])  (plain 64B rows --
//   consumed via L2 into REGISTERS, no LDS image, no padding, no swizzle)
// ---------------------------------------------------------------------------
__global__ void vq_prep_kernel(const float* __restrict__ emb,
                               float* __restrict__ en512,
                               uint8_t* __restrict__ ebf8) {
    int k = blockIdx.x * blockDim.x + threadIdx.x;
    if (k >= KCODES) return;
    const float4* e4 = reinterpret_cast<const float4*>(emb + k * DIM);
    float s0 = 0.f, s1 = 0.f, s2 = 0.f, s3 = 0.f;
#pragma unroll
    for (int j = 0; j < 8; ++j) {
        float4 v0 = e4[j * 2];
        float4 v1 = e4[j * 2 + 1];
        s0 = fmaf(v0.x, v0.x, s0); s1 = fmaf(v0.y, v0.y, s1);
        s2 = fmaf(v0.z, v0.z, s2); s3 = fmaf(v0.w, v0.w, s3);
        s0 = fmaf(v1.x, v1.x, s0); s1 = fmaf(v1.y, v1.y, s1);
        s2 = fmaf(v1.z, v1.z, s2); s3 = fmaf(v1.w, v1.w, s3);
        uint32_t lo = 0, hi = 0;
        lo = __builtin_amdgcn_cvt_pk_fp8_f32(-1024.f * v0.x, -1024.f * v0.y, lo, false);
        lo = __builtin_amdgcn_cvt_pk_fp8_f32(-1024.f * v0.z, -1024.f * v0.w, lo, true);
        hi = __builtin_amdgcn_cvt_pk_fp8_f32(-1024.f * v1.x, -1024.f * v1.y, hi, false);
        hi = __builtin_amdgcn_cvt_pk_fp8_f32(-1024.f * v1.z, -1024.f * v1.w, hi, true);
        uint2 p; p.x = lo; p.y = hi;
        *reinterpret_cast<uint2*>(&ebf8[k * DIM + (j << 3)]) = p;
    }
    en512[k] = 512.f * (1.0f + (s0 + s1) + (s2 + s3));
}

// ---------------------------------------------------------------------------
// Kernel B: REGISTER-RESIDENT CODEBOOK streaming VQ.
//   A-operand = codes (32 nf-tiles x 2 ks in 128 VGPRs, loaded once/wave),
//   B-operand = latent rows. D[m=code][n=row]: col n = lane&15 = latent row,
//   row m = code = nf*16 + lq*4 + r.
// Per wave: 8 chunks of 16 rows, grid-stride-free persistent assignment,
// next chunk's B prefetched under current score. NO barriers after prologue,
// NO LDS in the loop (2 KB en broadcast table only). 2 waves/SIMD by design.
//   512*(score+1) = en512[code] + fp8(x).fp8(-1024 e)  (en added post-MFMA)
//   key = (bits & ~511) | nf  -> min over nf -> reconstruct full code ->
//   min over r (in-lane) -> 2-shfl butterfly over lq. Tie -> smallest code.
//   loss row-sum = key/512 - 1 + ||x||^2 (exact xsq from fp32 regs).
// ---------------------------------------------------------------------------
__launch_bounds__(BLOCK, 2)
__global__ void vq_stream_kernel(const float* __restrict__ lat,
                                 const float* __restrict__ emb,
                                 const float* __restrict__ en512,
                                 const uint8_t* __restrict__ ebf8,
                                 float* __restrict__ outq,
                                 float* __restrict__ partials) {
    __shared__ float en_lds[KCODES];      // 2 KB broadcast table
    __shared__ float wsum_lds[BLOCK / 64];

    const int t = threadIdx.x;
    const int lane = t & 63, wid = t >> 6;
    const int l15 = lane & 15, lq = lane >> 4;
    const uint32_t wrow = ((uint32_t)blockIdx.x * (BLOCK / 64) + wid) * ROWS_PER_WAVE;

    en_lds[t] = en512[t];
    en_lds[t + BLOCK] = en512[t + BLOCK];

    // ---- codebook -> registers (once per wave; 32 KB from L2, fully unrolled
    // constant indices so acode stays in VGPRs -- rule #20)
    i64t acode[32][2];
#pragma unroll
    for (int nf = 0; nf < 32; ++nf) {
#pragma unroll
        for (int ks = 0; ks < 2; ++ks) {
            acode[nf][ks] = *reinterpret_cast<const i64t*>(
                ebf8 + (uint32_t)(nf * 16 + l15) * DIM + ks * 32 + lq * 8);
        }
    }
    __syncthreads();   // en_lds ready (only barrier before epilogue)

    float xsq = 0.f, lsum = 0.f;
    const f32x4* emb4 = reinterpret_cast<const f32x4*>(emb);
    f32x4* out4 = reinterpret_cast<f32x4*>(outq);

    float4 brA[2][2], brB[2][2];   // [ks][half] raw fp32 B, double-buffered

    auto load_b = [&](float4 (&br)[2][2], uint32_t row0) {
#pragma unroll
        for (int ks = 0; ks < 2; ++ks) {
            const float* xp = lat + (row0 + l15) * DIM + ks * 32 + lq * 8;
            br[ks][0] = reinterpret_cast<const float4*>(xp)[0];
            br[ks][1] = reinterpret_cast<const float4*>(xp)[1];
        }
    };

    auto process = [&](float4 (&br)[2][2], uint32_t row0) {
        // cvt B -> fp8 frags; exact ||x||^2 (lane holds 16 elems of row l15)
        i64t bfrag[2];
#pragma unroll
        for (int ks = 0; ks < 2; ++ks) {
            float4 v0 = br[ks][0], v1 = br[ks][1];
            xsq = fmaf(v0.x, v0.x, xsq); xsq = fmaf(v0.y, v0.y, xsq);
            xsq = fmaf(v0.z, v0.z, xsq); xsq = fmaf(v0.w, v0.w, xsq);
            xsq = fmaf(v1.x, v1.x, xsq); xsq = fmaf(v1.y, v1.y, xsq);
            xsq = fmaf(v1.z, v1.z, xsq); xsq = fmaf(v1.w, v1.w, xsq);
            uint32_t lo = 0, hi = 0;
            lo = __builtin_amdgcn_cvt_pk_fp8_f32(v0.x, v0.y, lo, false);
            lo = __builtin_amdgcn_cvt_pk_fp8_f32(v0.z, v0.w, lo, true);
            hi = __builtin_amdgcn_cvt_pk_fp8_f32(v1.x, v1.y, hi, false);
            hi = __builtin_amdgcn_cvt_pk_fp8_f32(v1.z, v1.w, hi, true);
            bfrag[ks] = (i64t)(((uint64_t)hi << 32) | (uint64_t)lo);
        }

        uint32_t kb[4];
#pragma unroll
        for (int r = 0; r < 4; ++r) kb[r] = 0xFFFFFFFFu;

        // score: 32 reg-only MFMA pairs; en added post-MFMA (512-grain keys,
        // low 5 bits = nf for in-lane tie-break = smallest code)
#pragma unroll
        for (int nf = 0; nf < 32; ++nf) {
            f32x4 acc = {0.f, 0.f, 0.f, 0.f};
            acc = __builtin_amdgcn_mfma_f32_16x16x32_fp8_fp8(acode[nf][0], bfrag[0], acc, 0, 0, 0);
            acc = __builtin_amdgcn_mfma_f32_16x16x32_fp8_fp8(acode[nf][1], bfrag[1], acc, 0, 0, 0);
            f32x4 en4 = *reinterpret_cast<const f32x4*>(&en_lds[nf * 16 + lq * 4]);
#pragma unroll
            for (int r = 0; r < 4; ++r) {
                float s = acc[r] + en4[r];
                uint32_t key = (__float_as_uint(s) & 0xFFFFFE00u) | (uint32_t)nf;
                kb[r] = min(kb[r], key);
            }
        }

        // reconstruct full code ids, fold r in-lane, butterfly over lq
        uint32_t full = 0xFFFFFFFFu;
#pragma unroll
        for (int r = 0; r < 4; ++r) {
            uint32_t code = (kb[r] & 31u) * 16u + (uint32_t)(lq * 4 + r);
            uint32_t fk = (kb[r] & 0xFFFFFE00u) | code;
            full = min(full, fk);
        }
        full = min(full, (uint32_t)__shfl_xor((int)full, 16, 64));
        full = min(full, (uint32_t)__shfl_xor((int)full, 32, 64));

        // loss: one lane per row contributes the key term
        if (lq == 0)
            lsum += __uint_as_float(full & 0xFFFFFE00u) * (1.f / 512.f) - 1.0f;

        // gather + write: row l15, lane covers chunks lq + 4i (64B/row/i)
        const uint32_t k = full & 511u;
        const uint32_t rbase = (row0 + l15) * 16;
#pragma unroll
        for (int i = 0; i < 4; ++i) {
            const int ch = lq + i * 4;
            out4[rbase + ch] = emb4[k * 16 + ch];
        }
    };

    // ---- persistent stream: 4 pairs of chunks, next-B prefetched under score
    load_b(brA, wrow);
    for (uint32_t cc = 0; cc < 4; ++cc) {
        const uint32_t r0 = wrow + cc * 32;
        load_b(brB, r0 + 16);            // flies under process(brA)
        process(brA, r0);
        if (cc < 3) load_b(brA, r0 + 32);  // flies under process(brB)
        process(brB, r0 + 16);
    }

    lsum += xsq;

    // ---- deterministic block reduce
#pragma unroll
    for (int off = 32; off > 0; off >>= 1)
        lsum += __shfl_down(lsum, off, 64);
    if (lane == 0) wsum_lds[wid] = lsum;
    __syncthreads();
    if (t == 0) {
        float s = 0.f;
#pragma unroll
        for (int w = 0; w < BLOCK / 64; ++w) s += wsum_lds[w];
        partials[blockIdx.x] = s;
    }
}

// ---------------------------------------------------------------------------
// Kernel C: reduce partials -> vq_loss = 1.25 * mean((q-x)^2)
// ---------------------------------------------------------------------------
__global__ void vq_loss_kernel(const float* __restrict__ partials,
                               float* __restrict__ loss) {
    float s = 0.f;
    for (int i = threadIdx.x; i < NBLK; i += 256) s += partials[i];
#pragma unroll
    for (int off = 32; off > 0; off >>= 1)
        s += __shfl_down(s, off, 64);
    __shared__ float wsum[4];
    const int lane = threadIdx.x & 63;
    const int wid = threadIdx.x >> 6;
    if (lane == 0) wsum[wid] = s;
    __syncthreads();
    if (threadIdx.x == 0) {
        float tsum = 0.f;
#pragma unroll
        for (int w = 0; w < 4; ++w) tsum += wsum[w];
        loss[0] = 1.25f * (tsum / (float)((size_t)NROWS * DIM));
    }
}

// ---------------------------------------------------------------------------
extern "C" void kernel_launch(void* const* d_in, const int* in_sizes, int n_in,
                              void* d_out, int out_size, void* d_ws, size_t ws_size,
                              hipStream_t stream) {
    const float* lat = (const float*)d_in[0];   // [B,S,D] fp32
    const float* emb = (const float*)d_in[1];   // [K,D]   fp32
    float* outq = (float*)d_out;                              // output 0
    float* loss = (float*)d_out + (size_t)NROWS * DIM;        // output 1

    // ws layout (bytes): [0,2048)        en512 f32[512]
    //                    [2048, 34816)   ebf8 fp8[512*64] (plain rows, -1024x)
    //                    [34816, 36864)  partials f32[512]
    float* en512 = (float*)d_ws;
    uint8_t* ebf8 = (uint8_t*)d_ws + 2048;
    float* partials = (float*)((char*)d_ws + 34816);

    vq_prep_kernel<<<2, 256, 0, stream>>>(emb, en512, ebf8);
    vq_stream_kernel<<<NBLK, BLOCK, 0, stream>>>(lat, emb, en512, ebf8, outq, partials);
    vq_loss_kernel<<<1, 256, 0, stream>>>(partials, loss);
}

// Round 16
// 43.718 us; speedup vs baseline: 2.3648x; 2.3648x over previous
//
#include <hip/hip_runtime.h>
#include <math.h>
#include <stdint.h>

#define KCODES 512
#define DIM 64
#define ROWB 72               // padded LDS/ws row stride in bytes (64 + 8 pad)
#define NROWS (64 * 4096)     // B*S = 262144
#define BLOCK 512             // 8 waves
#define ROWS_PER_WAVE 32      // TWO 16-row mf tiles per wave
#define BM ((BLOCK / 64) * ROWS_PER_WAVE)   // 256 rows per block
#define NBLK (NROWS / BM)                   // 1024 blocks; 4/CU resident

typedef float f32x4 __attribute__((ext_vector_type(4)));
typedef long long i64t;

typedef __attribute__((address_space(3))) uint32_t* lds_ptr_t;
typedef const __attribute__((address_space(1))) uint32_t* glb_ptr_t;

// ---------------------------------------------------------------------------
// Kernel A (prep, runs once): per code k
//   en512[k] = 512 * (1 + ||e_k||^2)      (exact fp32; acc-init, pre-scaled)
//   ebf8[k*72 + j*8 .. +7] = fp8_e4m3(-1024 * e_k[j*8..])   (padded rows;
//   pad bytes never read; padding lives in the ws image so linear
//   global_load_lds staging reproduces it in LDS).
// 72 B rows -> ds_read_b64 bank = (18*l15 + 2*c) % 32, injective over the
// 16-lane quarter -> conflict-free, no XOR swizzle anywhere. [verified R13]
// ---------------------------------------------------------------------------
__global__ void vq_prep_kernel(const float* __restrict__ emb,
                               float* __restrict__ en512,
                               uint8_t* __restrict__ ebf8) {
    int k = blockIdx.x * blockDim.x + threadIdx.x;
    if (k >= KCODES) return;
    const float4* e4 = reinterpret_cast<const float4*>(emb + k * DIM);
    float s0 = 0.f, s1 = 0.f, s2 = 0.f, s3 = 0.f;
#pragma unroll
    for (int j = 0; j < 8; ++j) {
        float4 v0 = e4[j * 2];
        float4 v1 = e4[j * 2 + 1];
        s0 = fmaf(v0.x, v0.x, s0); s1 = fmaf(v0.y, v0.y, s1);
        s2 = fmaf(v0.z, v0.z, s2); s3 = fmaf(v0.w, v0.w, s3);
        s0 = fmaf(v1.x, v1.x, s0); s1 = fmaf(v1.y, v1.y, s1);
        s2 = fmaf(v1.z, v1.z, s2); s3 = fmaf(v1.w, v1.w, s3);
        uint32_t lo = 0, hi = 0;
        lo = __builtin_amdgcn_cvt_pk_fp8_f32(-1024.f * v0.x, -1024.f * v0.y, lo, false);
        lo = __builtin_amdgcn_cvt_pk_fp8_f32(-1024.f * v0.z, -1024.f * v0.w, lo, true);
        hi = __builtin_amdgcn_cvt_pk_fp8_f32(-1024.f * v1.x, -1024.f * v1.y, hi, false);
        hi = __builtin_amdgcn_cvt_pk_fp8_f32(-1024.f * v1.z, -1024.f * v1.w, hi, true);
        uint2 p; p.x = lo; p.y = hi;
        *reinterpret_cast<uint2*>(&ebf8[k * ROWB + (j << 3)]) = p;
    }
    en512[k] = 512.f * (1.0f + (s0 + s1) + (s2 + s3));
}

// ---------------------------------------------------------------------------
// Kernel B: R13 core (fp8 MFMA, padded conflict-free LDS, packed-key argmin,
// loss-from-keys) with TWO mf tiles per wave (32 rows):
//  - E staged once per 256 rows (half the restage+barrier cost per row)
//  - each b0/b1 ds_read feeds 2 MFMAs (acc0, acc1)
//  - two independent umin chains per nf (ILP)
// 39 KB LDS -> 4 blocks/CU x 8 waves = 100% occupancy cap.
// ---------------------------------------------------------------------------
__launch_bounds__(BLOCK, 8)
__global__ void vq_mfma_kernel(const float* __restrict__ lat,
                               const float* __restrict__ emb,
                               const float* __restrict__ en512,
                               const uint8_t* __restrict__ ebf8,
                               float* __restrict__ outq,
                               float* __restrict__ partials) {
    __shared__ __align__(16) uint8_t e_lds[KCODES * ROWB];  // 36864 B, padded
    __shared__ float en_lds[KCODES];                        // 2 KB
    __shared__ float wsum_lds[BLOCK / 64];

    const int t = threadIdx.x;
    const int lane = t & 63, wid = t >> 6;
    const int l15 = lane & 15, lq = lane >> 4;

    // XCD-aware bijective swizzle (1024 % 8 == 0)
    const uint32_t bid = (blockIdx.x & 7) * (NBLK / 8) + (blockIdx.x >> 3);
    const uint32_t waverow = bid * BM + (uint32_t)wid * ROWS_PER_WAVE;

    // ---- stage E image (incl. pads): 2304 x 16B chunks, linear, once.
#pragma unroll
    for (int i = 0; i < 4; ++i) {
        int c = t + i * BLOCK;
        __builtin_amdgcn_global_load_lds(
            (glb_ptr_t)(const void*)(ebf8 + c * 16),
            (lds_ptr_t)(void*)(&e_lds[c * 16]), 16, 0, 0);
    }
    if (t < 256) {   // waves 0-3, wave-uniform branch
        int c = 2048 + t;
        __builtin_amdgcn_global_load_lds(
            (glb_ptr_t)(const void*)(ebf8 + c * 16),
            (lds_ptr_t)(void*)(&e_lds[c * 16]), 16, 0, 0);
    }

    // ---- A loads: 2 mf tiles x 2 ks halves, raw fp32 (8 x dwordx4 / lane).
    float4 araw[2][2][2];   // [mf][ks][half]
#pragma unroll
    for (int mf = 0; mf < 2; ++mf) {
#pragma unroll
        for (int ks = 0; ks < 2; ++ks) {
            const float* xp =
                lat + (waverow + mf * 16 + l15) * DIM + ks * 32 + lq * 8;
            araw[mf][ks][0] = reinterpret_cast<const float4*>(xp)[0];
            araw[mf][ks][1] = reinterpret_cast<const float4*>(xp)[1];
        }
    }
    en_lds[t] = en512[t];   // BLOCK == KCODES
    __syncthreads();        // vmcnt drain: E + en + A ready

    // ---- cvt A -> fp8 frags; exact ||x||^2 from fp32 regs
    float xsq = 0.f, lsum = 0.f;
    i64t afrag[2][2];
#pragma unroll
    for (int mf = 0; mf < 2; ++mf) {
#pragma unroll
        for (int ks = 0; ks < 2; ++ks) {
            float4 v0 = araw[mf][ks][0], v1 = araw[mf][ks][1];
            xsq = fmaf(v0.x, v0.x, xsq); xsq = fmaf(v0.y, v0.y, xsq);
            xsq = fmaf(v0.z, v0.z, xsq); xsq = fmaf(v0.w, v0.w, xsq);
            xsq = fmaf(v1.x, v1.x, xsq); xsq = fmaf(v1.y, v1.y, xsq);
            xsq = fmaf(v1.z, v1.z, xsq); xsq = fmaf(v1.w, v1.w, xsq);
            uint32_t lo = 0, hi = 0;
            lo = __builtin_amdgcn_cvt_pk_fp8_f32(v0.x, v0.y, lo, false);
            lo = __builtin_amdgcn_cvt_pk_fp8_f32(v0.z, v0.w, lo, true);
            hi = __builtin_amdgcn_cvt_pk_fp8_f32(v1.x, v1.y, hi, false);
            hi = __builtin_amdgcn_cvt_pk_fp8_f32(v1.z, v1.w, hi, true);
            afrag[mf][ks] = (i64t)(((uint64_t)hi << 32) | (uint64_t)lo);
        }
    }

    uint32_t best[2][4];
#pragma unroll
    for (int mf = 0; mf < 2; ++mf)
#pragma unroll
        for (int r = 0; r < 4; ++r) best[mf][r] = 0xFFFFFFFFu;

    // ---- score loop: each b0/b1 pair feeds 4 MFMAs (2 mf tiles x 2 ks).
#pragma unroll 4
    for (int nf = 0; nf < 32; ++nf) {
        const int n = nf * 16 + l15;
        const uint8_t* p = &e_lds[n * ROWB + (lq << 3)];
        i64t b0 = *reinterpret_cast<const i64t*>(p);        // elems 8lq..
        i64t b1 = *reinterpret_cast<const i64t*>(p + 32);   // elems 32+8lq..
        float en = en_lds[n];
        f32x4 acc0 = {en, en, en, en};
        f32x4 acc1 = {en, en, en, en};
        acc0 = __builtin_amdgcn_mfma_f32_16x16x32_fp8_fp8(afrag[0][0], b0, acc0, 0, 0, 0);
        acc0 = __builtin_amdgcn_mfma_f32_16x16x32_fp8_fp8(afrag[0][1], b1, acc0, 0, 0, 0);
        acc1 = __builtin_amdgcn_mfma_f32_16x16x32_fp8_fp8(afrag[1][0], b0, acc1, 0, 0, 0);
        acc1 = __builtin_amdgcn_mfma_f32_16x16x32_fp8_fp8(afrag[1][1], b1, acc1, 0, 0, 0);
        const uint32_t nn = (uint32_t)n;
#pragma unroll
        for (int r = 0; r < 4; ++r) {
            uint32_t k0 = (__float_as_uint(acc0[r]) & 0xFFFFFE00u) | nn;
            uint32_t k1 = (__float_as_uint(acc1[r]) & 0xFFFFFE00u) | nn;
            best[0][r] = min(best[0][r], k0);
            best[1][r] = min(best[1][r], k1);
        }
    }

    // ---- cross-lane umin butterfly: ALL 16 col-lanes end with row minima
#pragma unroll
    for (int off = 1; off < 16; off <<= 1) {
#pragma unroll
        for (int mf = 0; mf < 2; ++mf)
#pragma unroll
            for (int r = 0; r < 4; ++r) {
                uint32_t o = (uint32_t)__shfl_xor((int)best[mf][r], off, 64);
                best[mf][r] = min(best[mf][r], o);
            }
    }

    // ---- loss from keys: row-sum (q-x)^2 = key/512 - 1 + ||x||^2
    if (l15 == 0) {
#pragma unroll
        for (int mf = 0; mf < 2; ++mf)
#pragma unroll
            for (int r = 0; r < 4; ++r)
                lsum = fmaf(__uint_as_float(best[mf][r] & 0xFFFFFE00u),
                            (1.f / 512.f), lsum - 1.0f);
    }

    // ---- per-wave gather: lane (lq,l15) writes chunk l15 of row
    // waverow + mf*16 + lq*4 + r; emb (64 KB fp32) is L2-resident.
    const float4* emb4 = reinterpret_cast<const float4*>(emb);
    float4* out4 = reinterpret_cast<float4*>(outq);
#pragma unroll
    for (int mf = 0; mf < 2; ++mf) {
#pragma unroll
        for (int r = 0; r < 4; ++r) {
            const uint32_t k = best[mf][r] & 511u;
            const uint32_t grow = waverow + mf * 16 + lq * 4 + r;
            float4 e4 = emb4[k * 16 + l15];
            out4[grow * 16 + l15] = e4;
        }
    }

    lsum += xsq;

    // ---- deterministic block reduce
#pragma unroll
    for (int off = 32; off > 0; off >>= 1)
        lsum += __shfl_down(lsum, off, 64);
    if (lane == 0) wsum_lds[wid] = lsum;
    __syncthreads();
    if (t == 0) {
        float s = 0.f;
#pragma unroll
        for (int w = 0; w < BLOCK / 64; ++w) s += wsum_lds[w];
        partials[blockIdx.x] = s;
    }
}

// ---------------------------------------------------------------------------
// Kernel C: reduce partials -> vq_loss = 1.25 * mean((q-x)^2)
// ---------------------------------------------------------------------------
__global__ void vq_loss_kernel(const float* __restrict__ partials,
                               float* __restrict__ loss) {
    float s = 0.f;
    for (int i = threadIdx.x; i < NBLK; i += 256) s += partials[i];
#pragma unroll
    for (int off = 32; off > 0; off >>= 1)
        s += __shfl_down(s, off, 64);
    __shared__ float wsum[4];
    const int lane = threadIdx.x & 63;
    const int wid = threadIdx.x >> 6;
    if (lane == 0) wsum[wid] = s;
    __syncthreads();
    if (threadIdx.x == 0) {
        float tsum = 0.f;
#pragma unroll
        for (int w = 0; w < 4; ++w) tsum += wsum[w];
        loss[0] = 1.25f * (tsum / (float)((size_t)NROWS * DIM));
    }
}

// ---------------------------------------------------------------------------
extern "C" void kernel_launch(void* const* d_in, const int* in_sizes, int n_in,
                              void* d_out, int out_size, void* d_ws, size_t ws_size,
                              hipStream_t stream) {
    const float* lat = (const float*)d_in[0];   // [B,S,D] fp32
    const float* emb = (const float*)d_in[1];   // [K,D]   fp32
    float* outq = (float*)d_out;                              // output 0
    float* loss = (float*)d_out + (size_t)NROWS * DIM;        // output 1

    // ws layout (bytes): [0,2048)        en512 f32[512]
    //                    [2048, 38912)   ebf8 fp8[512*72] (padded rows, -1024x)
    //                    [38912, 43008)  partials f32[1024]
    float* en512 = (float*)d_ws;
    uint8_t* ebf8 = (uint8_t*)d_ws + 2048;
    float* partials = (float*)((char*)d_ws + 38912);

    vq_prep_kernel<<<2, 256, 0, stream>>>(emb, en512, ebf8);
    vq_mfma_kernel<<<NBLK, BLOCK, 0, stream>>>(lat, emb, en512, ebf8, outq, partials);
    vq_loss_kernel<<<1, 256, 0, stream>>>(partials, loss);
}

// Round 17
// 40.208 us; speedup vs baseline: 2.5712x; 1.0873x over previous
//
#include <hip/hip_runtime.h>
#include <math.h>
#include <stdint.h>

#define KCODES 512
#define DIM 64
#define ROWB 72               // padded LDS/ws row stride in bytes (64 + 8 pad)
#define NROWS (64 * 4096)     // B*S = 262144
#define BLOCK 512             // 8 waves
#define ROWS_PER_WAVE 16      // one 16-row mf tile per wave
#define BM ((BLOCK / 64) * ROWS_PER_WAVE)   // 128 rows per block
#define NBLK (NROWS / BM)                   // 2048 blocks; 4/CU resident, 8 gens

typedef float f32x4 __attribute__((ext_vector_type(4)));
typedef long long i64t;

typedef __attribute__((address_space(3))) uint32_t* lds_ptr_t;
typedef const __attribute__((address_space(1))) uint32_t* glb_ptr_t;

// ---------------------------------------------------------------------------
// Kernel A (prep, runs once): per code k
//   en512[k] = 512 * (1 + ||e_k||^2)      (exact fp32; acc-init, pre-scaled)
//   ebf8[k*72 + j*8 .. +7] = fp8_e4m3(-1024 * e_k[j*8..])   (padded rows;
//   pad bytes never read; padding lives in the ws image so linear
//   global_load_lds staging reproduces it in LDS).
// 72 B rows -> ds_read_b64 bank = (18*l15 + 2*c) % 32, injective over the
// 16-lane quarter -> conflict-free, no XOR swizzle anywhere. [verified R13]
// ---------------------------------------------------------------------------
__global__ void vq_prep_kernel(const float* __restrict__ emb,
                               float* __restrict__ en512,
                               uint8_t* __restrict__ ebf8) {
    int k = blockIdx.x * blockDim.x + threadIdx.x;
    if (k >= KCODES) return;
    const float4* e4 = reinterpret_cast<const float4*>(emb + k * DIM);
    float s0 = 0.f, s1 = 0.f, s2 = 0.f, s3 = 0.f;
#pragma unroll
    for (int j = 0; j < 8; ++j) {
        float4 v0 = e4[j * 2];
        float4 v1 = e4[j * 2 + 1];
        s0 = fmaf(v0.x, v0.x, s0); s1 = fmaf(v0.y, v0.y, s1);
        s2 = fmaf(v0.z, v0.z, s2); s3 = fmaf(v0.w, v0.w, s3);
        s0 = fmaf(v1.x, v1.x, s0); s1 = fmaf(v1.y, v1.y, s1);
        s2 = fmaf(v1.z, v1.z, s2); s3 = fmaf(v1.w, v1.w, s3);
        uint32_t lo = 0, hi = 0;
        lo = __builtin_amdgcn_cvt_pk_fp8_f32(-1024.f * v0.x, -1024.f * v0.y, lo, false);
        lo = __builtin_amdgcn_cvt_pk_fp8_f32(-1024.f * v0.z, -1024.f * v0.w, lo, true);
        hi = __builtin_amdgcn_cvt_pk_fp8_f32(-1024.f * v1.x, -1024.f * v1.y, hi, false);
        hi = __builtin_amdgcn_cvt_pk_fp8_f32(-1024.f * v1.z, -1024.f * v1.w, hi, true);
        uint2 p; p.x = lo; p.y = hi;
        *reinterpret_cast<uint2*>(&ebf8[k * ROWB + (j << 3)]) = p;
    }
    en512[k] = 512.f * (1.0f + (s0 + s1) + (s2 + s3));
}

// ---------------------------------------------------------------------------
// Kernel B (R13, best verified 39.5 us; + A-loads issued before E-staging):
// fp8 MFMA scoring + packed-key argmin + per-wave gather + loss.
//   512*(score+1) = en512[k] + fp8(x) . fp8(-1024 e_k)   (acc-init = en512)
//   positive -> as_uint monotone; key = (bits & ~511) | k ; umin; tie -> min k.
//   loss row-sum = key/512 - 1 + ||x||^2 (exact xsq from fp32 regs).
// 39 KB LDS -> 4 blocks/CU x 8 waves = 100% occupancy cap; NBLK=2048 gives
// 8 generations of block turnover. A-loads (HBM, ~900cyc) enter the vmcnt
// FIFO before E-staging (L2, ~200cyc); one barrier drains all.
// ---------------------------------------------------------------------------
__launch_bounds__(BLOCK, 8)
__global__ void vq_mfma_kernel(const float* __restrict__ lat,
                               const float* __restrict__ emb,
                               const float* __restrict__ en512,
                               const uint8_t* __restrict__ ebf8,
                               float* __restrict__ outq,
                               float* __restrict__ partials) {
    __shared__ __align__(16) uint8_t e_lds[KCODES * ROWB];  // 36864 B, padded
    __shared__ float en_lds[KCODES];                        // 2 KB
    __shared__ float wsum_lds[BLOCK / 64];

    const int t = threadIdx.x;
    const int lane = t & 63, wid = t >> 6;
    const int l15 = lane & 15, lq = lane >> 4;

    // XCD-aware bijective swizzle (2048 % 8 == 0)
    const uint32_t bid = (blockIdx.x & 7) * (NBLK / 8) + (blockIdx.x >> 3);
    const uint32_t waverow = bid * BM + (uint32_t)wid * ROWS_PER_WAVE;

    // ---- A loads FIRST (longest latency): 16 rows/wave, raw fp32.
    float4 araw[2][2];   // [ks][half]
#pragma unroll
    for (int ks = 0; ks < 2; ++ks) {
        const float* xp = lat + (waverow + l15) * DIM + ks * 32 + lq * 8;
        araw[ks][0] = reinterpret_cast<const float4*>(xp)[0];
        araw[ks][1] = reinterpret_cast<const float4*>(xp)[1];
    }

    // ---- stage E image (incl. pads): 2304 x 16B chunks, linear.
#pragma unroll
    for (int i = 0; i < 4; ++i) {
        int c = t + i * BLOCK;
        __builtin_amdgcn_global_load_lds(
            (glb_ptr_t)(const void*)(ebf8 + c * 16),
            (lds_ptr_t)(void*)(&e_lds[c * 16]), 16, 0, 0);
    }
    if (t < 256) {   // waves 0-3, wave-uniform branch
        int c = 2048 + t;
        __builtin_amdgcn_global_load_lds(
            (glb_ptr_t)(const void*)(ebf8 + c * 16),
            (lds_ptr_t)(void*)(&e_lds[c * 16]), 16, 0, 0);
    }
    en_lds[t] = en512[t];   // BLOCK == KCODES
    __syncthreads();        // vmcnt drain: A + E + en ready (only barrier)

    // ---- cvt A -> fp8 frags (k = 8*lq + b per ks-half); exact ||x||^2
    float xsq = 0.f, lsum = 0.f;
    i64t afrag[2];
#pragma unroll
    for (int ks = 0; ks < 2; ++ks) {
        float4 v0 = araw[ks][0], v1 = araw[ks][1];
        xsq = fmaf(v0.x, v0.x, xsq); xsq = fmaf(v0.y, v0.y, xsq);
        xsq = fmaf(v0.z, v0.z, xsq); xsq = fmaf(v0.w, v0.w, xsq);
        xsq = fmaf(v1.x, v1.x, xsq); xsq = fmaf(v1.y, v1.y, xsq);
        xsq = fmaf(v1.z, v1.z, xsq); xsq = fmaf(v1.w, v1.w, xsq);
        uint32_t lo = 0, hi = 0;
        lo = __builtin_amdgcn_cvt_pk_fp8_f32(v0.x, v0.y, lo, false);
        lo = __builtin_amdgcn_cvt_pk_fp8_f32(v0.z, v0.w, lo, true);
        hi = __builtin_amdgcn_cvt_pk_fp8_f32(v1.x, v1.y, hi, false);
        hi = __builtin_amdgcn_cvt_pk_fp8_f32(v1.z, v1.w, hi, true);
        afrag[ks] = (i64t)(((uint64_t)hi << 32) | (uint64_t)lo);
    }

    uint32_t best[4];
#pragma unroll
    for (int r = 0; r < 4; ++r) best[r] = 0xFFFFFFFFu;

    // ---- score loop: 32 groups of 16 codes; conflict-free b64 LDS reads.
#pragma unroll 4
    for (int nf = 0; nf < 32; ++nf) {
        const int n = nf * 16 + l15;
        const uint8_t* p = &e_lds[n * ROWB + (lq << 3)];
        i64t b0 = *reinterpret_cast<const i64t*>(p);        // elems 8lq..
        i64t b1 = *reinterpret_cast<const i64t*>(p + 32);   // elems 32+8lq..
        float en = en_lds[n];
        f32x4 acc = {en, en, en, en};
        acc = __builtin_amdgcn_mfma_f32_16x16x32_fp8_fp8(afrag[0], b0, acc, 0, 0, 0);
        acc = __builtin_amdgcn_mfma_f32_16x16x32_fp8_fp8(afrag[1], b1, acc, 0, 0, 0);
        const uint32_t nn = (uint32_t)n;
#pragma unroll
        for (int r = 0; r < 4; ++r) {
            uint32_t k = (__float_as_uint(acc[r]) & 0xFFFFFE00u) | nn;
            best[r] = min(best[r], k);
        }
    }

    // ---- cross-lane umin butterfly: ALL 16 col-lanes end with row minima
#pragma unroll
    for (int off = 1; off < 16; off <<= 1) {
#pragma unroll
        for (int r = 0; r < 4; ++r) {
            uint32_t o = (uint32_t)__shfl_xor((int)best[r], off, 64);
            best[r] = min(best[r], o);
        }
    }

    // ---- loss from keys: row-sum (q-x)^2 = key/512 - 1 + ||x||^2
    if (l15 == 0) {
#pragma unroll
        for (int r = 0; r < 4; ++r)
            lsum = fmaf(__uint_as_float(best[r] & 0xFFFFFE00u),
                        (1.f / 512.f), lsum - 1.0f);
    }

    // ---- per-wave gather: lane (lq,l15) writes chunk l15 of row
    // waverow + lq*4 + r; emb (128 KB fp32) is L2-resident.
    const float4* emb4 = reinterpret_cast<const float4*>(emb);
    float4* out4 = reinterpret_cast<float4*>(outq);
#pragma unroll
    for (int r = 0; r < 4; ++r) {
        const uint32_t k = best[r] & 511u;
        const uint32_t grow = waverow + lq * 4 + r;
        float4 e4 = emb4[k * 16 + l15];
        out4[grow * 16 + l15] = e4;
    }

    lsum += xsq;

    // ---- deterministic block reduce
#pragma unroll
    for (int off = 32; off > 0; off >>= 1)
        lsum += __shfl_down(lsum, off, 64);
    if (lane == 0) wsum_lds[wid] = lsum;
    __syncthreads();
    if (t == 0) {
        float s = 0.f;
#pragma unroll
        for (int w = 0; w < BLOCK / 64; ++w) s += wsum_lds[w];
        partials[blockIdx.x] = s;
    }
}

// ---------------------------------------------------------------------------
// Kernel C: reduce partials -> vq_loss = 1.25 * mean((q-x)^2)
// ---------------------------------------------------------------------------
__global__ void vq_loss_kernel(const float* __restrict__ partials,
                               float* __restrict__ loss) {
    float s = 0.f;
    for (int i = threadIdx.x; i < NBLK; i += 256) s += partials[i];
#pragma unroll
    for (int off = 32; off > 0; off >>= 1)
        s += __shfl_down(s, off, 64);
    __shared__ float wsum[4];
    const int lane = threadIdx.x & 63;
    const int wid = threadIdx.x >> 6;
    if (lane == 0) wsum[wid] = s;
    __syncthreads();
    if (threadIdx.x == 0) {
        float tsum = 0.f;
#pragma unroll
        for (int w = 0; w < 4; ++w) tsum += wsum[w];
        loss[0] = 1.25f * (tsum / (float)((size_t)NROWS * DIM));
    }
}

// ---------------------------------------------------------------------------
extern "C" void kernel_launch(void* const* d_in, const int* in_sizes, int n_in,
                              void* d_out, int out_size, void* d_ws, size_t ws_size,
                              hipStream_t stream) {
    const float* lat = (const float*)d_in[0];   // [B,S,D] fp32
    const float* emb = (const float*)d_in[1];   // [K,D]   fp32
    float* outq = (float*)d_out;                              // output 0
    float* loss = (float*)d_out + (size_t)NROWS * DIM;        // output 1

    // ws layout (bytes): [0,2048)        en512 f32[512]
    //                    [2048, 38912)   ebf8 fp8[512*72] (padded rows, -1024x)
    //                    [38912, 47104)  partials f32[2048]
    float* en512 = (float*)d_ws;
    uint8_t* ebf8 = (uint8_t*)d_ws + 2048;
    float* partials = (float*)((char*)d_ws + 38912);

    vq_prep_kernel<<<2, 256, 0, stream>>>(emb, en512, ebf8);
    vq_mfma_kernel<<<NBLK, BLOCK, 0, stream>>>(lat, emb, en512, ebf8, outq, partials);
    vq_loss_kernel<<<1, 256, 0, stream>>>(partials, loss);
}